// Round 10
// baseline (1155.384 us; speedup 1.0000x reference)
//
#include <hip/hip_runtime.h>
#include <hip/hip_bf16.h>

// R10: independent-wave streaming, split kernels.
// kA: scores = relu(X@W1+b1)@W2+b2 for all 409600 flat (m,n) rows.
//     Each wave owns 16-row tiles; all 24 float4 A-loads issued before the
//     consume phase (sched_barrier-pinned); B from L2-hot W1p; no barriers.
// kB: per-wave-owns-m: softmax + v-GEMM(K=256) + weighted pooling + lout.

#define M_ 4096
#define N_ 100
#define E_ 128
#define R_ (M_ * N_)          // 409600 flat rows; 25600 16-row tiles exactly

typedef __bf16 bf16x8 __attribute__((ext_vector_type(8)));
typedef float  f32x4  __attribute__((ext_vector_type(4)));

// W1p[ck][n][j] = bf16(W1[ck*8+j][n]), ck<48 ; WRp same for WR, ck<32 ;
// Wot[e][k] = Wo[k][e] (f32, for coalesced lout reads)
__global__ void prep_weights(const float* __restrict__ W1, const float* __restrict__ WR,
                             const float* __restrict__ Wo,
                             __bf16* __restrict__ W1p, __bf16* __restrict__ WRp,
                             float* __restrict__ Wot) {
    int i = blockIdx.x * 256 + threadIdx.x;   // 384*256 = 98304 = 49152+32768+16384
    if (i < 48 * 128 * 8) {
        int ck = i >> 10, n = (i >> 3) & 127, j = i & 7;
        W1p[i] = (__bf16)W1[(ck * 8 + j) * 128 + n];
    } else if (i < 48 * 128 * 8 + 32 * 128 * 8) {
        int t = i - 48 * 128 * 8;
        int ck = t >> 10, n = (t >> 3) & 127, j = t & 7;
        WRp[t] = (__bf16)WR[(ck * 8 + j) * 128 + n];
    } else {
        int t = i - (48 * 128 * 8 + 32 * 128 * 8);
        int e = t >> 7, k = t & 127;
        Wot[t] = Wo[k * 128 + e];
    }
}

__device__ __forceinline__ bf16x8 cvt8(const float4 lo, const float4 hi) {
    bf16x8 r;
    r[0] = (__bf16)lo.x; r[1] = (__bf16)lo.y; r[2] = (__bf16)lo.z; r[3] = (__bf16)lo.w;
    r[4] = (__bf16)hi.x; r[5] = (__bf16)hi.y; r[6] = (__bf16)hi.z; r[7] = (__bf16)hi.w;
    return r;
}

// ---------------- kernel A ----------------
__global__ __launch_bounds__(512, 3) void kA(
    const float* __restrict__ pus, const float* __restrict__ pis,
    const float* __restrict__ pss,
    const __bf16* __restrict__ W1p, const float* __restrict__ b1,
    const float* __restrict__ W2, const float* __restrict__ b2,
    float* __restrict__ scores)
{
    __shared__ float w2s[128], b1s[128];
    if (threadIdx.x < 128) { w2s[threadIdx.x] = W2[threadIdx.x]; b1s[threadIdx.x] = b1[threadIdx.x]; }
    __syncthreads();

    const int tid = threadIdx.x;
    const int lane = tid & 63;
    const int wid  = tid >> 6;
    const int g    = lane >> 4;
    const int l15  = lane & 15;
    const int gw = blockIdx.x * 8 + wid;
    const int NW = gridDim.x * 8;
    const float b2v = b2[0];

    float w2v[8], b1v[8];
    #pragma unroll
    for (int cf = 0; cf < 8; ++cf) { w2v[cf] = w2s[cf * 16 + l15]; b1v[cf] = b1s[cf * 16 + l15]; }

    for (int t = gw; t < R_ / 16; t += NW) {
        const long rowoff = ((long)t * 16 + l15) * E_;
        float4 pv[24];
        // issue ALL tile loads (pinned above the consume phase)
        #pragma unroll
        for (int kc = 0; kc < 12; ++kc) {
            const float* __restrict__ src = (kc < 4) ? pus : (kc < 8) ? pis : pss;
            const float* p = src + rowoff + (kc & 3) * 32 + g * 8;
            pv[2 * kc]     = *reinterpret_cast<const float4*>(p);
            pv[2 * kc + 1] = *reinterpret_cast<const float4*>(p + 4);
        }
        __builtin_amdgcn_sched_barrier(0);

        f32x4 acc[8];
        #pragma unroll
        for (int cf = 0; cf < 8; ++cf) acc[cf] = (f32x4){0.f, 0.f, 0.f, 0.f};

        #pragma unroll
        for (int kc = 0; kc < 12; ++kc) {
            bf16x8 af = cvt8(pv[2 * kc], pv[2 * kc + 1]);
            const __bf16* __restrict__ wp = W1p + ((kc * 4 + g) << 10) + l15 * 8;
            #pragma unroll
            for (int cf = 0; cf < 8; ++cf) {
                bf16x8 bf = *reinterpret_cast<const bf16x8*>(wp + (cf << 7));
                acc[cf] = __builtin_amdgcn_mfma_f32_16x16x32_bf16(af, bf, acc[cf], 0, 0, 0);
            }
        }

        // epilogue (R7-verified layout: col=cf*16+l15, row=g*4+r)
        #pragma unroll
        for (int r = 0; r < 4; ++r) {
            float ps = 0.f;
            #pragma unroll
            for (int cf = 0; cf < 8; ++cf)
                ps += fmaxf(acc[cf][r] + b1v[cf], 0.f) * w2v[cf];
            ps += __shfl_xor(ps, 1);
            ps += __shfl_xor(ps, 2);
            ps += __shfl_xor(ps, 4);
            ps += __shfl_xor(ps, 8);
            if (l15 == 0)
                scores[t * 16 + g * 4 + r] = ps + b2v;
        }
    }
}

// ---------------- kernel B ----------------
__global__ __launch_bounds__(512, 3) void kB(
    const float* __restrict__ Cc, const float* __restrict__ pss,
    const __bf16* __restrict__ WRp, const float* __restrict__ bR,
    const float* __restrict__ Wot, const float* __restrict__ bo,
    const float* __restrict__ scores, float* __restrict__ out)
{
    __shared__ float wsc[8][112];   // per-wave softmax weights (112 = 7*16 rows)
    __shared__ float prs[8][128];   // per-wave pair vector
    __shared__ float bRs[128];
    if (threadIdx.x < 128) bRs[threadIdx.x] = bR[threadIdx.x];
    __syncthreads();

    const int tid = threadIdx.x;
    const int lane = tid & 63;
    const int wid  = tid >> 6;
    const int g    = lane >> 4;
    const int l15  = lane & 15;
    const int gw = blockIdx.x * 8 + wid;
    const int NW = gridDim.x * 8;

    float bRv[8];
    #pragma unroll
    for (int cf = 0; cf < 8; ++cf) bRv[cf] = bRs[cf * 16 + l15];

    for (int m = gw; m < M_; m += NW) {
        // ---- softmax over this m's 100 scores (wave-private) ----
        const float* sp = scores + (long)m * N_;
        float s0 = (lane < N_) ? sp[lane] : -3e38f;
        float s1 = (lane + 64 < N_) ? sp[lane + 64] : -3e38f;
        float mx = fmaxf(s0, s1);
        #pragma unroll
        for (int off = 1; off < 64; off <<= 1) mx = fmaxf(mx, __shfl_xor(mx, off));
        float e0 = (lane < N_) ? __expf(s0 - mx) : 0.f;
        float e1 = (lane + 64 < N_) ? __expf(s1 - mx) : 0.f;
        float sum = e0 + e1;
        #pragma unroll
        for (int off = 1; off < 64; off <<= 1) sum += __shfl_xor(sum, off);
        float inv = 1.f / sum;
        wsc[wid][lane] = e0 * inv;
        if (lane < 48) wsc[wid][64 + lane] = e1 * inv;   // rows 64..111 (>=100 -> 0)

        float psum[8];
        #pragma unroll
        for (int cf = 0; cf < 8; ++cf) psum[cf] = 0.f;

        // ---- 7 tiles of 16 rows, K=256 ([C|pss]) ----
        for (int tt = 0; tt < 7; ++tt) {
            int rim = tt * 16 + l15; if (rim > N_ - 1) rim = N_ - 1;  // clamp pad (w=0)
            const long rowoff = ((long)m * N_ + rim) * E_;
            float4 pv[16];
            #pragma unroll
            for (int kc = 0; kc < 8; ++kc) {
                const float* __restrict__ src = (kc < 4) ? Cc : pss;
                const float* p = src + rowoff + (kc & 3) * 32 + g * 8;
                pv[2 * kc]     = *reinterpret_cast<const float4*>(p);
                pv[2 * kc + 1] = *reinterpret_cast<const float4*>(p + 4);
            }
            __builtin_amdgcn_sched_barrier(0);

            f32x4 acc[8];
            #pragma unroll
            for (int cf = 0; cf < 8; ++cf) acc[cf] = (f32x4){0.f, 0.f, 0.f, 0.f};

            #pragma unroll
            for (int kc = 0; kc < 8; ++kc) {
                bf16x8 af = cvt8(pv[2 * kc], pv[2 * kc + 1]);
                const __bf16* __restrict__ wp = WRp + ((kc * 4 + g) << 10) + l15 * 8;
                #pragma unroll
                for (int cf = 0; cf < 8; ++cf) {
                    bf16x8 bf = *reinterpret_cast<const bf16x8*>(wp + (cf << 7));
                    acc[cf] = __builtin_amdgcn_mfma_f32_16x16x32_bf16(af, bf, acc[cf], 0, 0, 0);
                }
            }
            // pooling: rows of this tile are g*4+r
            float wg[4];
            #pragma unroll
            for (int r = 0; r < 4; ++r) wg[r] = wsc[wid][tt * 16 + g * 4 + r];
            #pragma unroll
            for (int cf = 0; cf < 8; ++cf)
                #pragma unroll
                for (int r = 0; r < 4; ++r)
                    psum[cf] += wg[r] * fmaxf(acc[cf][r] + bRv[cf], 0.f);
        }

        // reduce over row-groups: after xor 16,32 every lane has pair[cf*16+l15]
        #pragma unroll
        for (int cf = 0; cf < 8; ++cf) {
            psum[cf] += __shfl_xor(psum[cf], 16);
            psum[cf] += __shfl_xor(psum[cf], 32);
            prs[wid][cf * 16 + l15] = psum[cf];   // duplicate writes, same value
        }

        // ---- lout (wave-private): out[e] = relu(bo[e] + pair . Wot[e]) ----
        float o0 = 0.f, o1 = 0.f;
        #pragma unroll 8
        for (int kb = 0; kb < 32; ++kb) {
            float4 pk  = *reinterpret_cast<const float4*>(&prs[wid][kb * 4]);
            float4 wv0 = *reinterpret_cast<const float4*>(Wot + (long)lane * 128 + kb * 4);
            float4 wv1 = *reinterpret_cast<const float4*>(Wot + (long)(lane + 64) * 128 + kb * 4);
            o0 += pk.x * wv0.x + pk.y * wv0.y + pk.z * wv0.z + pk.w * wv0.w;
            o1 += pk.x * wv1.x + pk.y * wv1.y + pk.z * wv1.z + pk.w * wv1.w;
        }
        out[(long)m * 128 + lane]      = fmaxf(o0 + bo[lane], 0.f);
        out[(long)m * 128 + lane + 64] = fmaxf(o1 + bo[lane + 64], 0.f);
    }
}

extern "C" void kernel_launch(void* const* d_in, const int* in_sizes, int n_in,
                              void* d_out, int out_size, void* d_ws, size_t ws_size,
                              hipStream_t stream) {
    const float* pus = (const float*)d_in[2];
    const float* pis = (const float*)d_in[3];
    const float* pss = (const float*)d_in[4];
    const float* C   = (const float*)d_in[5];
    const float* W1  = (const float*)d_in[6];
    const float* b1  = (const float*)d_in[7];
    const float* W2  = (const float*)d_in[8];
    const float* b2  = (const float*)d_in[9];
    const float* WR  = (const float*)d_in[10];
    const float* bR  = (const float*)d_in[11];
    const float* Wo  = (const float*)d_in[12];
    const float* bo  = (const float*)d_in[13];
    (void)in_sizes; (void)n_in; (void)ws_size;

    // ws: scores f32[R_] | W1p bf16[48*1024] | WRp bf16[32*1024] | Wot f32[16384]
    float*  scores = (float*)d_ws;
    __bf16* W1p = (__bf16*)((char*)d_ws + (size_t)R_ * 4);
    __bf16* WRp = W1p + 48 * 1024;
    float*  Wot = (float*)(WRp + 32 * 1024);

    prep_weights<<<384, 256, 0, stream>>>(W1, WR, Wo, W1p, WRp, Wot);
    kA<<<640, 512, 0, stream>>>(pus, pis, pss, W1p, b1, W2, b2, scores);
    kB<<<512, 512, 0, stream>>>(C, pss, WRp, bR, Wot, bo, scores, (float*)d_out);
}